// Round 1
// baseline (756.962 us; speedup 1.0000x reference)
//
#include <hip/hip_runtime.h>
#include <math.h>

#define NB 32
#define NC 512
#define HW 4096
#define NSEG 128
#define NCLS 19

// ---------------------------------------------------------------------------
// K1: downsample mask -> ids (uint8), per-segment counts
// ---------------------------------------------------------------------------
__global__ __launch_bounds__(256) void k_ids_counts(const int* __restrict__ mask,
                                                    unsigned char* __restrict__ ids,
                                                    float* __restrict__ counts) {
  int b = blockIdx.x;
  int t = threadIdx.x;
  __shared__ int cnt[NSEG + 1];
  if (t < NSEG + 1) cnt[t] = 0;
  __syncthreads();
  const int* mb = mask + (size_t)b * 262144;  // 512*512
  for (int p = t; p < HW; p += 256) {
    int i = p >> 6, j = p & 63;
    int id = mb[i * 4096 + j * 8];  // mask[b, 8i, 8j]
    ids[(size_t)b * HW + p] = (unsigned char)id;
    atomicAdd(&cnt[id], 1);
  }
  __syncthreads();
  if (t < NSEG) counts[b * NSEG + t] = (float)cnt[t + 1];
}

// ---------------------------------------------------------------------------
// K2: segment means. Block = (channel-chunk cc, batch b); 64 channels/block.
// LDS bins[129][65]: row 0 is a dummy sink for id==0 (branch-free scatter),
// stride 65 -> bank (s+c)%32, conflict-free for same-c different-s scatter.
// ---------------------------------------------------------------------------
__global__ __launch_bounds__(256) void k_segmeans(const float* __restrict__ x,
                                                  const unsigned char* __restrict__ ids,
                                                  const float* __restrict__ counts,
                                                  float* __restrict__ means) {
  int b = blockIdx.y;
  int c0 = blockIdx.x * 64;
  int t = threadIdx.x;
  __shared__ float bins[129 * 65];
  __shared__ float invc[NSEG];
  for (int i = t; i < 129 * 65; i += 256) bins[i] = 0.f;
  if (t < NSEG) {
    float c = counts[b * NSEG + t];
    invc[t] = c > 0.f ? 1.f / c : 0.f;
  }
  // ids for this batch into registers: thread t owns pixels k*1024 + 4t .. +3
  uchar4 myid[4];
  const uchar4* idp = (const uchar4*)(ids + (size_t)b * HW);
#pragma unroll
  for (int k = 0; k < 4; ++k) myid[k] = idp[k * 256 + t];
  __syncthreads();

  const float4* xb = (const float4*)x + (size_t)(b * NC) * 1024;
  for (int c = 0; c < 64; ++c) {
    const float4* xc = xb + (size_t)(c0 + c) * 1024;
#pragma unroll
    for (int k = 0; k < 4; ++k) {
      float4 v = xc[k * 256 + t];
      uchar4 id = myid[k];
      atomicAdd(&bins[(int)id.x * 65 + c], v.x);
      atomicAdd(&bins[(int)id.y * 65 + c], v.y);
      atomicAdd(&bins[(int)id.z * 65 + c], v.z);
      atomicAdd(&bins[(int)id.w * 65 + c], v.w);
    }
  }
  __syncthreads();
  for (int i = t; i < NSEG * 64; i += 256) {
    int s = i >> 6, c = i & 63;
    means[((size_t)b * NSEG + s) * NC + c0 + c] = bins[(s + 1) * 65 + c] * invc[s];
  }
}

// ---------------------------------------------------------------------------
// K3: attention logits a[b][s] = relu(means[b,s,:]@Wa1 + ba1) @ Wa2 + ba2
// Block = (s-tile of 16, batch). Thread t owns Wa1 columns t and t+256.
// ---------------------------------------------------------------------------
__global__ __launch_bounds__(256) void k_att(const float* __restrict__ means,
                                             const float* __restrict__ Wa1,
                                             const float* __restrict__ ba1,
                                             const float* __restrict__ Wa2,
                                             const float* __restrict__ ba2,
                                             float* __restrict__ alog) {
  int b = blockIdx.y, st = blockIdx.x;
  int t = threadIdx.x;
  __shared__ float mt[16 * 512];
  __shared__ float red[4][16];
  const float4* m4 = (const float4*)(means + ((size_t)b * NSEG + st * 16) * NC);
  float4* mt4 = (float4*)mt;
#pragma unroll
  for (int i = 0; i < 8; ++i) mt4[i * 256 + t] = m4[i * 256 + t];
  __syncthreads();

  float2 acc[16];
#pragma unroll
  for (int r = 0; r < 16; ++r) acc[r] = make_float2(0.f, 0.f);

  for (int k4 = 0; k4 < 128; ++k4) {
    int k = k4 * 4;
    float wa0[4], wa1c[4];
#pragma unroll
    for (int kk = 0; kk < 4; ++kk) {
      wa0[kk] = Wa1[(size_t)(k + kk) * 512 + t];
      wa1c[kk] = Wa1[(size_t)(k + kk) * 512 + t + 256];
    }
#pragma unroll
    for (int r = 0; r < 16; ++r) {
      float4 m = *(const float4*)&mt[r * 512 + k];
      acc[r].x = fmaf(m.x, wa0[0], fmaf(m.y, wa0[1], fmaf(m.z, wa0[2], fmaf(m.w, wa0[3], acc[r].x))));
      acc[r].y = fmaf(m.x, wa1c[0], fmaf(m.y, wa1c[1], fmaf(m.z, wa1c[2], fmaf(m.w, wa1c[3], acc[r].y))));
    }
  }

  float b1a = ba1[t], b1b = ba1[t + 256];
  float w2a = Wa2[t], w2b = Wa2[t + 256];
  int lane = t & 63, wid = t >> 6;
#pragma unroll
  for (int r = 0; r < 16; ++r) {
    float v = fmaxf(acc[r].x + b1a, 0.f) * w2a + fmaxf(acc[r].y + b1b, 0.f) * w2b;
#pragma unroll
    for (int off = 32; off > 0; off >>= 1) v += __shfl_down(v, off, 64);
    if (lane == 0) red[wid][r] = v;
  }
  __syncthreads();
  if (t < 16) {
    alog[b * NSEG + st * 16 + t] = red[0][t] + red[1][t] + red[2][t] + red[3][t] + ba2[0];
  }
}

// ---------------------------------------------------------------------------
// K4: softmax(att) -> wm[c] = sum_s att[s]*means[b,s,c] ->
//     logits[b,c] = wm @ Wh[:,c] + bh[c]  (since sum(att)=1), + loss partial
// ---------------------------------------------------------------------------
__global__ __launch_bounds__(256) void k_head(const float* __restrict__ means,
                                              const float* __restrict__ alog,
                                              const float* __restrict__ Wh,
                                              const float* __restrict__ bh,
                                              const float* __restrict__ target,
                                              float* __restrict__ out,
                                              float* __restrict__ wloss) {
  int b = blockIdx.x, t = threadIdx.x;
  __shared__ float att[NSEG];
  __shared__ float wm[NC];
  __shared__ float sred[4];
  __shared__ float sval;
  int lane = t & 63, wid = t >> 6;

  float l = (t < NSEG) ? alog[b * NSEG + t] : -INFINITY;
  // max-reduce over 256 threads
  float v = l;
#pragma unroll
  for (int off = 32; off > 0; off >>= 1) v = fmaxf(v, __shfl_down(v, off, 64));
  if (lane == 0) sred[wid] = v;
  __syncthreads();
  if (t == 0) sval = fmaxf(fmaxf(sred[0], sred[1]), fmaxf(sred[2], sred[3]));
  __syncthreads();
  float mx = sval;
  float e = (t < NSEG) ? expf(l - mx) : 0.f;
  if (t < NSEG) att[t] = e;
  v = e;
#pragma unroll
  for (int off = 32; off > 0; off >>= 1) v += __shfl_down(v, off, 64);
  if (lane == 0) sred[wid] = v;
  __syncthreads();
  if (t == 0) sval = sred[0] + sred[1] + sred[2] + sred[3];
  __syncthreads();
  float isum = 1.f / sval;
  if (t < NSEG) att[t] *= isum;
  __syncthreads();

  // weighted mean over segments: wm[c] = sum_s att[s] * means[b,s,c]
  const float* mb = means + (size_t)b * NSEG * NC;
  for (int c = t; c < NC; c += 256) {
    float s = 0.f;
    for (int sg = 0; sg < NSEG; ++sg) s = fmaf(att[sg], mb[(size_t)sg * NC + c], s);
    wm[c] = s;
  }
  __syncthreads();

  __shared__ float lg[NCLS];
  if (t < NCLS) {
    float s = bh[t];
    for (int k = 0; k < NC; ++k) s = fmaf(wm[k], Wh[k * NCLS + t], s);
    lg[t] = s;
    out[b * NCLS + t] = s;
  }
  __syncthreads();
  if (t < 64) {
    float term = 0.f;
    if (t < NCLS) {
      float xg = lg[t];
      term = fmaxf(xg, 0.f) - xg * target[b * NCLS + t] + log1pf(expf(-fabsf(xg)));
    }
#pragma unroll
    for (int off = 32; off > 0; off >>= 1) term += __shfl_down(term, off, 64);
    if (t == 0) wloss[b] = term;
  }
}

// ---------------------------------------------------------------------------
// K5: final loss reduce
// ---------------------------------------------------------------------------
__global__ void k_loss(const float* __restrict__ wloss, float* __restrict__ out) {
  int t = threadIdx.x;
  float v = (t < NB) ? wloss[t] : 0.f;
#pragma unroll
  for (int off = 32; off > 0; off >>= 1) v += __shfl_down(v, off, 64);
  if (t == 0) out[NB * NCLS] = v * (1.f / (NB * NCLS));
}

extern "C" void kernel_launch(void* const* d_in, const int* in_sizes, int n_in,
                              void* d_out, int out_size, void* d_ws, size_t ws_size,
                              hipStream_t stream) {
  const float* x = (const float*)d_in[0];
  const int* mask = (const int*)d_in[1];
  const float* target = (const float*)d_in[2];
  const float* Wa1 = (const float*)d_in[3];
  const float* ba1 = (const float*)d_in[4];
  const float* Wa2 = (const float*)d_in[5];
  const float* ba2 = (const float*)d_in[6];
  const float* Wh = (const float*)d_in[7];
  const float* bh = (const float*)d_in[8];
  float* out = (float*)d_out;

  char* ws = (char*)d_ws;
  float* means = (float*)ws;                              // 32*128*512*4 = 8388608 B
  unsigned char* ids = (unsigned char*)(ws + 8388608);    // 32*4096      = 131072 B
  float* counts = (float*)(ws + 8519680);                 // 32*128*4     = 16384 B
  float* alog = (float*)(ws + 8536064);                   // 32*128*4     = 16384 B
  float* wloss = (float*)(ws + 8552448);                  // 32*4         = 128 B

  k_ids_counts<<<NB, 256, 0, stream>>>(mask, ids, counts);
  k_segmeans<<<dim3(8, NB), 256, 0, stream>>>(x, ids, counts, means);
  k_att<<<dim3(8, NB), 256, 0, stream>>>(means, Wa1, ba1, Wa2, ba2, alog);
  k_head<<<NB, 256, 0, stream>>>(means, alog, Wh, bh, target, out, wloss);
  k_loss<<<1, 64, 0, stream>>>(wloss, out);
}

// Round 2
// 718.920 us; speedup vs baseline: 1.0529x; 1.0529x over previous
//
#include <hip/hip_runtime.h>
#include <math.h>

#define NB 32
#define NC 512
#define HW 4096
#define NSEG 128
#define NCLS 19

// ws layout (bytes):
//   sums   [32][128][512] f32 : off 0        size 8388608
//   counts [32][128]      f32 : off 8388608  size 16384
//   alog   [32][128]      f32 : off 8404992  size 16384
//   wloss  [32]           f32 : off 8421376  size 128
//   ids    [32][4096]     u8  : off 8421504  size 131072
#define OFF_COUNTS 8388608
#define OFF_ALOG   8404992
#define OFF_WLOSS  8421376
#define OFF_IDS    8421504
#define ZERO_F4    525312   // (sums+counts) bytes / 16

// ---------------------------------------------------------------------------
// K0: zero sums + counts (ws is poisoned 0xAA before every call)
// ---------------------------------------------------------------------------
__global__ __launch_bounds__(256) void k_zero(float4* __restrict__ p) {
  int i = blockIdx.x * 1024 + threadIdx.x;
  float4 z = make_float4(0.f, 0.f, 0.f, 0.f);
#pragma unroll
  for (int j = 0; j < 4; ++j) {
    int idx = i + j * 256;
    if (idx < ZERO_F4) p[idx] = z;
  }
}

// ---------------------------------------------------------------------------
// K1: downsample mask -> ids (uint8), per-segment counts (global atomics)
// grid (4 row-chunks, 32 batches)
// ---------------------------------------------------------------------------
__global__ __launch_bounds__(256) void k_ids_counts(const int* __restrict__ mask,
                                                    unsigned char* __restrict__ ids,
                                                    float* __restrict__ counts) {
  int rq = blockIdx.x, b = blockIdx.y;
  int t = threadIdx.x;
  __shared__ int cnt[NSEG + 1];
  if (t < NSEG + 1) cnt[t] = 0;
  __syncthreads();
  const int* mb = mask + (size_t)b * 262144;  // 512*512
  int p0 = rq * 1024 + t * 4;
  uchar4 w;
  unsigned char* wp = (unsigned char*)&w;
#pragma unroll
  for (int j = 0; j < 4; ++j) {
    int p = p0 + j;
    int i = p >> 6, jj = p & 63;
    int id = mb[i * 4096 + jj * 8];  // mask[b, 8i, 8j]
    wp[j] = (unsigned char)id;
    atomicAdd(&cnt[id], 1);
  }
  *(uchar4*)(ids + (size_t)b * HW + p0) = w;
  __syncthreads();
  if (t < NSEG) atomicAdd(&counts[b * NSEG + t], (float)cnt[t + 1]);
}

// ---------------------------------------------------------------------------
// K2: segment sums. grid (8 ch-chunks, 4 pixel-quarters, 32 batches) = 1024.
// 8 independent float4 loads per iteration for MLP-free latency hiding,
// LDS bins row stride 65 (bank (s+c)%32), global atomic flush of partials.
// ---------------------------------------------------------------------------
__global__ __launch_bounds__(256) void k_segmeans(const float* __restrict__ x,
                                                  const unsigned char* __restrict__ ids,
                                                  float* __restrict__ sums) {
  int cc = blockIdx.x, pq = blockIdx.y, b = blockIdx.z;
  int t = threadIdx.x;
  __shared__ float bins[129 * 65];
  for (int i = t; i < 129 * 65; i += 256) bins[i] = 0.f;
  uchar4 myid = ((const uchar4*)(ids + (size_t)b * HW + pq * 1024))[t];
  __syncthreads();

  const float* xb = x + ((size_t)b * NC + cc * 64) * HW + pq * 1024 + 4 * t;
  for (int c = 0; c < 64; c += 8) {
    float4 v[8];
#pragma unroll
    for (int u = 0; u < 8; ++u) v[u] = *(const float4*)(xb + (size_t)(c + u) * HW);
#pragma unroll
    for (int u = 0; u < 8; ++u) {
      int cb = c + u;
      atomicAdd(&bins[(int)myid.x * 65 + cb], v[u].x);
      atomicAdd(&bins[(int)myid.y * 65 + cb], v[u].y);
      atomicAdd(&bins[(int)myid.z * 65 + cb], v[u].z);
      atomicAdd(&bins[(int)myid.w * 65 + cb], v[u].w);
    }
  }
  __syncthreads();
  for (int i = t; i < NSEG * 64; i += 256) {
    int s = i >> 6, c = i & 63;
    float v = bins[(s + 1) * 65 + c];
    if (v != 0.f) atomicAdd(&sums[((size_t)b * NSEG + s) * NC + cc * 64 + c], v);
  }
}

// ---------------------------------------------------------------------------
// K3: attention logits. grid (16 s-tiles of 8, 32 batches) = 512 blocks.
// Normalization (1/count) folded into the LDS staging of the means tile.
// ---------------------------------------------------------------------------
__global__ __launch_bounds__(256) void k_att(const float* __restrict__ sums,
                                             const float* __restrict__ counts,
                                             const float* __restrict__ Wa1,
                                             const float* __restrict__ ba1,
                                             const float* __restrict__ Wa2,
                                             const float* __restrict__ ba2,
                                             float* __restrict__ alog) {
  int st = blockIdx.x, b = blockIdx.y;
  int t = threadIdx.x;
  __shared__ float mt[8 * 512];
  __shared__ float red[4][8];
  const float4* m4 = (const float4*)(sums + ((size_t)b * NSEG + st * 8) * NC);
  float4* mt4 = (float4*)mt;
#pragma unroll
  for (int i = 0; i < 4; ++i) {
    int idx = i * 256 + t;
    int r = idx >> 7;
    float cn = counts[b * NSEG + st * 8 + r];
    float inv = cn > 0.f ? 1.f / cn : 0.f;
    float4 mv = m4[idx];
    mv.x *= inv; mv.y *= inv; mv.z *= inv; mv.w *= inv;
    mt4[idx] = mv;
  }
  __syncthreads();

  float2 acc[8];
#pragma unroll
  for (int r = 0; r < 8; ++r) acc[r] = make_float2(0.f, 0.f);

  for (int k4 = 0; k4 < 128; ++k4) {
    int k = k4 * 4;
    float wa0[4], wa1c[4];
#pragma unroll
    for (int kk = 0; kk < 4; ++kk) {
      wa0[kk]  = Wa1[(size_t)(k + kk) * 512 + t];
      wa1c[kk] = Wa1[(size_t)(k + kk) * 512 + t + 256];
    }
#pragma unroll
    for (int r = 0; r < 8; ++r) {
      float4 m = *(const float4*)&mt[r * 512 + k];
      acc[r].x = fmaf(m.x, wa0[0],  fmaf(m.y, wa0[1],  fmaf(m.z, wa0[2],  fmaf(m.w, wa0[3],  acc[r].x))));
      acc[r].y = fmaf(m.x, wa1c[0], fmaf(m.y, wa1c[1], fmaf(m.z, wa1c[2], fmaf(m.w, wa1c[3], acc[r].y))));
    }
  }

  float b1a = ba1[t], b1b = ba1[t + 256];
  float w2a = Wa2[t], w2b = Wa2[t + 256];
  int lane = t & 63, wid = t >> 6;
#pragma unroll
  for (int r = 0; r < 8; ++r) {
    float v = fmaxf(acc[r].x + b1a, 0.f) * w2a + fmaxf(acc[r].y + b1b, 0.f) * w2b;
#pragma unroll
    for (int off = 32; off > 0; off >>= 1) v += __shfl_down(v, off, 64);
    if (lane == 0) red[wid][r] = v;
  }
  __syncthreads();
  if (t < 8) {
    alog[b * NSEG + st * 8 + t] = red[0][t] + red[1][t] + red[2][t] + red[3][t] + ba2[0];
  }
}

// ---------------------------------------------------------------------------
// K4: softmax -> weighted mean (att scaled by 1/count) -> logits -> loss part
// ---------------------------------------------------------------------------
__global__ __launch_bounds__(256) void k_head(const float* __restrict__ sums,
                                              const float* __restrict__ counts,
                                              const float* __restrict__ alog,
                                              const float* __restrict__ Wh,
                                              const float* __restrict__ bh,
                                              const float* __restrict__ target,
                                              float* __restrict__ out,
                                              float* __restrict__ wloss) {
  int b = blockIdx.x, t = threadIdx.x;
  __shared__ float att[NSEG];
  __shared__ float wm[NC];
  __shared__ float sred[4];
  __shared__ float sval;
  __shared__ float part[8][20];
  __shared__ float lg[NCLS];
  int lane = t & 63, wid = t >> 6;

  float l = (t < NSEG) ? alog[b * NSEG + t] : -INFINITY;
  float v = l;
#pragma unroll
  for (int off = 32; off > 0; off >>= 1) v = fmaxf(v, __shfl_down(v, off, 64));
  if (lane == 0) sred[wid] = v;
  __syncthreads();
  if (t == 0) sval = fmaxf(fmaxf(sred[0], sred[1]), fmaxf(sred[2], sred[3]));
  __syncthreads();
  float mx = sval;
  float e = (t < NSEG) ? expf(l - mx) : 0.f;
  v = e;
#pragma unroll
  for (int off = 32; off > 0; off >>= 1) v += __shfl_down(v, off, 64);
  if (lane == 0) sred[wid] = v;
  __syncthreads();
  if (t == 0) sval = sred[0] + sred[1] + sred[2] + sred[3];
  __syncthreads();
  float isum = 1.f / sval;
  if (t < NSEG) {
    float cn = counts[b * NSEG + t];
    float inv = cn > 0.f ? 1.f / cn : 0.f;
    att[t] = e * isum * inv;  // fold 1/count into attention weight
  }
  __syncthreads();

  // wm[c] = sum_s att[s] * sums[b,s,c]
  const float* mb = sums + (size_t)b * NSEG * NC;
  {
    float s0 = 0.f, s1 = 0.f;
    for (int sg = 0; sg < NSEG; ++sg) {
      float a = att[sg];
      s0 = fmaf(a, mb[(size_t)sg * NC + t], s0);
      s1 = fmaf(a, mb[(size_t)sg * NC + t + 256], s1);
    }
    wm[t] = s0;
    wm[t + 256] = s1;
  }
  __syncthreads();

  // logits[cls] = wm @ Wh[:,cls] + bh[cls]; 8 k-groups x 19 classes = 152 thr
  if (t < 152) {
    int g = t / NCLS, cls = t - g * NCLS;
    float p = 0.f;
#pragma unroll 8
    for (int i = 0; i < 64; ++i) {
      int k = g + 8 * i;
      p = fmaf(wm[k], Wh[k * NCLS + cls], p);
    }
    part[g][cls] = p;
  }
  __syncthreads();
  if (t < NCLS) {
    float s = bh[t];
#pragma unroll
    for (int g = 0; g < 8; ++g) s += part[g][t];
    lg[t] = s;
    out[b * NCLS + t] = s;
  }
  __syncthreads();
  if (t < 64) {
    float term = 0.f;
    if (t < NCLS) {
      float xg = lg[t];
      term = fmaxf(xg, 0.f) - xg * target[b * NCLS + t] + log1pf(expf(-fabsf(xg)));
    }
#pragma unroll
    for (int off = 32; off > 0; off >>= 1) term += __shfl_down(term, off, 64);
    if (t == 0) wloss[b] = term;
  }
}

// ---------------------------------------------------------------------------
// K5: final loss reduce
// ---------------------------------------------------------------------------
__global__ void k_loss(const float* __restrict__ wloss, float* __restrict__ out) {
  int t = threadIdx.x;
  float v = (t < NB) ? wloss[t] : 0.f;
#pragma unroll
  for (int off = 32; off > 0; off >>= 1) v += __shfl_down(v, off, 64);
  if (t == 0) out[NB * NCLS] = v * (1.f / (NB * NCLS));
}

extern "C" void kernel_launch(void* const* d_in, const int* in_sizes, int n_in,
                              void* d_out, int out_size, void* d_ws, size_t ws_size,
                              hipStream_t stream) {
  const float* x = (const float*)d_in[0];
  const int* mask = (const int*)d_in[1];
  const float* target = (const float*)d_in[2];
  const float* Wa1 = (const float*)d_in[3];
  const float* ba1 = (const float*)d_in[4];
  const float* Wa2 = (const float*)d_in[5];
  const float* ba2 = (const float*)d_in[6];
  const float* Wh = (const float*)d_in[7];
  const float* bh = (const float*)d_in[8];
  float* out = (float*)d_out;

  char* ws = (char*)d_ws;
  float* sums = (float*)ws;
  float* counts = (float*)(ws + OFF_COUNTS);
  float* alog = (float*)(ws + OFF_ALOG);
  float* wloss = (float*)(ws + OFF_WLOSS);
  unsigned char* ids = (unsigned char*)(ws + OFF_IDS);

  k_zero<<<513, 256, 0, stream>>>((float4*)ws);
  k_ids_counts<<<dim3(4, NB), 256, 0, stream>>>(mask, ids, counts);
  k_segmeans<<<dim3(8, 4, NB), 256, 0, stream>>>(x, ids, sums);
  k_att<<<dim3(16, NB), 256, 0, stream>>>(sums, counts, Wa1, ba1, Wa2, ba2, alog);
  k_head<<<NB, 256, 0, stream>>>(sums, counts, alog, Wh, bh, target, out, wloss);
  k_loss<<<1, 64, 0, stream>>>(wloss, out);
}

// Round 3
// 552.873 us; speedup vs baseline: 1.3691x; 1.3003x over previous
//
#include <hip/hip_runtime.h>
#include <math.h>

#define NB 32
#define NC 512
#define HW 4096
#define NSEG 128
#define NCLS 19

// ws layout (bytes):
//   sums   [32][128][512] f32 : off 0        size 8388608
//   counts [32][128]      f32 : off 8388608  size 16384
//   alog   [32][128]      f32 : off 8404992  size 16384
//   wloss  [32]           f32 : off 8421376  size 128
//   ids    [32][4096]     u8  : off 8421504  size 131072
#define OFF_COUNTS 8388608
#define OFF_ALOG   8404992
#define OFF_WLOSS  8421376
#define OFF_IDS    8421504
#define ZERO_F4    525312   // (sums+counts) bytes / 16 == 513*1024 exactly

// ---------------------------------------------------------------------------
// K0: zero sums + counts (ws poisoned 0xAA before every call)
// ---------------------------------------------------------------------------
__global__ __launch_bounds__(256) void k_zero(float4* __restrict__ p) {
  int i = blockIdx.x * 1024 + threadIdx.x;
  float4 z = make_float4(0.f, 0.f, 0.f, 0.f);
#pragma unroll
  for (int j = 0; j < 4; ++j) p[i + j * 256] = z;
}

// ---------------------------------------------------------------------------
// K1: downsample mask -> ids (u8) + per-segment counts
// ---------------------------------------------------------------------------
__global__ __launch_bounds__(256) void k_ids_counts(const int* __restrict__ mask,
                                                    unsigned char* __restrict__ ids,
                                                    float* __restrict__ counts) {
  int rq = blockIdx.x, b = blockIdx.y;
  int t = threadIdx.x;
  __shared__ int cnt[NSEG + 1];
  if (t < NSEG + 1) cnt[t] = 0;
  __syncthreads();
  const int* mb = mask + (size_t)b * 262144;
  int p0 = rq * 1024 + t * 4;
  uchar4 wv;
  unsigned char* wp = (unsigned char*)&wv;
#pragma unroll
  for (int j = 0; j < 4; ++j) {
    int p = p0 + j;
    int i = p >> 6, jj = p & 63;
    int id = mb[i * 4096 + jj * 8];
    wp[j] = (unsigned char)id;
    atomicAdd(&cnt[id], 1);
  }
  *(uchar4*)(ids + (size_t)b * HW + p0) = wv;
  __syncthreads();
  if (t < NSEG) atomicAdd(&counts[b * NSEG + t], (float)cnt[t + 1]);
}

// ---------------------------------------------------------------------------
// K2: segment sums, atomic-free scatter.
// grid (8 ch-chunks, 4 px-quarters, 32 b). Per block: 64 ch x 1024 px.
// Loop over 16 tiles of 64 px:
//   stage x[64px][64ch] into LDS tile (coalesced loads, lanes=pixels),
//   scatter with lanes=channels: wave w owns segments with id%4==w ->
//   plain LDS RMW, conflict-free banks (stride-65 rows), no atomics.
// Next tile's loads are register-double-buffered past the scatter phase.
// ---------------------------------------------------------------------------
__global__ __launch_bounds__(256) void k_segmeans(const float* __restrict__ x,
                                                  const unsigned char* __restrict__ ids,
                                                  float* __restrict__ sums) {
  int cc = blockIdx.x, pq = blockIdx.y, b = blockIdx.z;
  int t = threadIdx.x;
  int w = t >> 6;       // wave id (scatter: segment ownership class)
  int lane = t & 63;    // scatter: channel lane
  __shared__ float bins[129 * 65];   // [seg][ch], row 0 unused-by-flush sink
  __shared__ float tile[64 * 65];    // [p_local][ch], stride 65
  __shared__ unsigned char lids[1024];

  for (int i = t; i < 129 * 65; i += 256) bins[i] = 0.f;
  ((uchar4*)lids)[t] = ((const uchar4*)(ids + (size_t)b * HW + pq * 1024))[t];

  int l16 = t & 15;     // staging: pixel sub-group (4 px each)
  int r0 = t >> 4;      // staging: channel row base (0..15)
  const float* xbase = x + ((size_t)(b * NC + cc * 64)) * HW + pq * 1024 + 4 * l16;

  float4 v[4], vn[4];
#pragma unroll
  for (int rr = 0; rr < 4; ++rr)
    v[rr] = *(const float4*)(xbase + (size_t)(r0 + rr * 16) * HW);
  __syncthreads();

  for (int ti = 0; ti < 16; ++ti) {
    // write current tile: tile[p*65 + c]
#pragma unroll
    for (int rr = 0; rr < 4; ++rr) {
      int c = r0 + rr * 16;
      int p = 4 * l16;
      tile[(p + 0) * 65 + c] = v[rr].x;
      tile[(p + 1) * 65 + c] = v[rr].y;
      tile[(p + 2) * 65 + c] = v[rr].z;
      tile[(p + 3) * 65 + c] = v[rr].w;
    }
    __syncthreads();
    // prefetch next tile (overlaps with scatter below)
    if (ti < 15) {
#pragma unroll
      for (int rr = 0; rr < 4; ++rr)
        vn[rr] = *(const float4*)(xbase + (size_t)(r0 + rr * 16) * HW + (ti + 1) * 64);
    }
    // scatter: wave-uniform id per pixel; wave w owns id%4==w rows
    int pbase = ti * 64;
#pragma unroll 4
    for (int j = 0; j < 64; ++j) {
      int s = lids[pbase + j];
      if ((s & 3) == w) {
        bins[s * 65 + lane] += tile[j * 65 + lane];
      }
    }
    __syncthreads();
#pragma unroll
    for (int rr = 0; rr < 4; ++rr) v[rr] = vn[rr];
  }

  // flush partials (4 pq-blocks contend per sums element)
  for (int i = t; i < NSEG * 64; i += 256) {
    int s = (i >> 6) + 1, c = i & 63;
    float vv = bins[s * 65 + c];
    if (vv != 0.f) atomicAdd(&sums[((size_t)b * NSEG + (s - 1)) * NC + cc * 64 + c], vv);
  }
}

// ---------------------------------------------------------------------------
// K3: attention logits, grid (16 s-tiles of 8, 32 b). Wa1 register-prefetch.
// ---------------------------------------------------------------------------
__global__ __launch_bounds__(256) void k_att(const float* __restrict__ sums,
                                             const float* __restrict__ counts,
                                             const float* __restrict__ Wa1,
                                             const float* __restrict__ ba1,
                                             const float* __restrict__ Wa2,
                                             const float* __restrict__ ba2,
                                             float* __restrict__ alog) {
  int st = blockIdx.x, b = blockIdx.y;
  int t = threadIdx.x;
  __shared__ float mt[8 * 512];
  __shared__ float red[4][8];
  const float4* m4 = (const float4*)(sums + ((size_t)b * NSEG + st * 8) * NC);
  float4* mt4 = (float4*)mt;
#pragma unroll
  for (int i = 0; i < 4; ++i) {
    int idx = i * 256 + t;
    int r = idx >> 7;
    float cn = counts[b * NSEG + st * 8 + r];
    float inv = cn > 0.f ? 1.f / cn : 0.f;
    float4 mv = m4[idx];
    mv.x *= inv; mv.y *= inv; mv.z *= inv; mv.w *= inv;
    mt4[idx] = mv;
  }
  __syncthreads();

  float2 acc[8];
#pragma unroll
  for (int r = 0; r < 8; ++r) acc[r] = make_float2(0.f, 0.f);

  float wc0[4], wc1[4], wn0[4], wn1[4];
#pragma unroll
  for (int kk = 0; kk < 4; ++kk) {
    wc0[kk] = Wa1[(size_t)kk * 512 + t];
    wc1[kk] = Wa1[(size_t)kk * 512 + t + 256];
  }
  for (int k4 = 0; k4 < 128; ++k4) {
    if (k4 < 127) {
      int k = (k4 + 1) * 4;
#pragma unroll
      for (int kk = 0; kk < 4; ++kk) {
        wn0[kk] = Wa1[(size_t)(k + kk) * 512 + t];
        wn1[kk] = Wa1[(size_t)(k + kk) * 512 + t + 256];
      }
    }
    int k = k4 * 4;
#pragma unroll
    for (int r = 0; r < 8; ++r) {
      float4 m = *(const float4*)&mt[r * 512 + k];
      acc[r].x = fmaf(m.x, wc0[0], fmaf(m.y, wc0[1], fmaf(m.z, wc0[2], fmaf(m.w, wc0[3], acc[r].x))));
      acc[r].y = fmaf(m.x, wc1[0], fmaf(m.y, wc1[1], fmaf(m.z, wc1[2], fmaf(m.w, wc1[3], acc[r].y))));
    }
#pragma unroll
    for (int kk = 0; kk < 4; ++kk) { wc0[kk] = wn0[kk]; wc1[kk] = wn1[kk]; }
  }

  float b1a = ba1[t], b1b = ba1[t + 256];
  float w2a = Wa2[t], w2b = Wa2[t + 256];
  int lane = t & 63, wid = t >> 6;
#pragma unroll
  for (int r = 0; r < 8; ++r) {
    float v = fmaxf(acc[r].x + b1a, 0.f) * w2a + fmaxf(acc[r].y + b1b, 0.f) * w2b;
#pragma unroll
    for (int off = 32; off > 0; off >>= 1) v += __shfl_down(v, off, 64);
    if (lane == 0) red[wid][r] = v;
  }
  __syncthreads();
  if (t < 8) {
    alog[b * NSEG + st * 8 + t] = red[0][t] + red[1][t] + red[2][t] + red[3][t] + ba2[0];
  }
}

// ---------------------------------------------------------------------------
// K4: softmax -> weighted mean -> logits -> loss partial
// ---------------------------------------------------------------------------
__global__ __launch_bounds__(256) void k_head(const float* __restrict__ sums,
                                              const float* __restrict__ counts,
                                              const float* __restrict__ alog,
                                              const float* __restrict__ Wh,
                                              const float* __restrict__ bh,
                                              const float* __restrict__ target,
                                              float* __restrict__ out,
                                              float* __restrict__ wloss) {
  int b = blockIdx.x, t = threadIdx.x;
  __shared__ float att[NSEG];
  __shared__ float wm[NC];
  __shared__ float sred[4];
  __shared__ float sval;
  __shared__ float part[8][20];
  __shared__ float lg[NCLS];
  int lane = t & 63, wid = t >> 6;

  float l = (t < NSEG) ? alog[b * NSEG + t] : -INFINITY;
  float v = l;
#pragma unroll
  for (int off = 32; off > 0; off >>= 1) v = fmaxf(v, __shfl_down(v, off, 64));
  if (lane == 0) sred[wid] = v;
  __syncthreads();
  if (t == 0) sval = fmaxf(fmaxf(sred[0], sred[1]), fmaxf(sred[2], sred[3]));
  __syncthreads();
  float mx = sval;
  float e = (t < NSEG) ? expf(l - mx) : 0.f;
  v = e;
#pragma unroll
  for (int off = 32; off > 0; off >>= 1) v += __shfl_down(v, off, 64);
  if (lane == 0) sred[wid] = v;
  __syncthreads();
  if (t == 0) sval = sred[0] + sred[1] + sred[2] + sred[3];
  __syncthreads();
  float isum = 1.f / sval;
  if (t < NSEG) {
    float cn = counts[b * NSEG + t];
    float inv = cn > 0.f ? 1.f / cn : 0.f;
    att[t] = e * isum * inv;  // fold 1/count into attention weight
  }
  __syncthreads();

  // wm[c] = sum_s att[s]*sums[b,s,c] ; 4 independent FMA chains / 8 loads per 2 segs
  const float* mb = sums + (size_t)b * NSEG * NC;
  {
    float s0 = 0.f, s1 = 0.f, s2 = 0.f, s3 = 0.f;
#pragma unroll 4
    for (int sg = 0; sg < NSEG; sg += 2) {
      float a0 = att[sg], a1 = att[sg + 1];
      const float* rp = mb + (size_t)sg * NC;
      s0 = fmaf(a0, rp[t], s0);
      s1 = fmaf(a0, rp[t + 256], s1);
      s2 = fmaf(a1, rp[NC + t], s2);
      s3 = fmaf(a1, rp[NC + t + 256], s3);
    }
    wm[t] = s0 + s2;
    wm[t + 256] = s1 + s3;
  }
  __syncthreads();

  if (t < 152) {
    int g = t / NCLS, cls = t - g * NCLS;
    float p = 0.f;
#pragma unroll 8
    for (int i = 0; i < 64; ++i) {
      int k = g + 8 * i;
      p = fmaf(wm[k], Wh[k * NCLS + cls], p);
    }
    part[g][cls] = p;
  }
  __syncthreads();
  if (t < NCLS) {
    float s = bh[t];
#pragma unroll
    for (int g = 0; g < 8; ++g) s += part[g][t];
    lg[t] = s;
    out[b * NCLS + t] = s;
  }
  __syncthreads();
  if (t < 64) {
    float term = 0.f;
    if (t < NCLS) {
      float xg = lg[t];
      term = fmaxf(xg, 0.f) - xg * target[b * NCLS + t] + log1pf(expf(-fabsf(xg)));
    }
#pragma unroll
    for (int off = 32; off > 0; off >>= 1) term += __shfl_down(term, off, 64);
    if (t == 0) wloss[b] = term;
  }
}

// ---------------------------------------------------------------------------
// K5: final loss reduce
// ---------------------------------------------------------------------------
__global__ void k_loss(const float* __restrict__ wloss, float* __restrict__ out) {
  int t = threadIdx.x;
  float v = (t < NB) ? wloss[t] : 0.f;
#pragma unroll
  for (int off = 32; off > 0; off >>= 1) v += __shfl_down(v, off, 64);
  if (t == 0) out[NB * NCLS] = v * (1.f / (NB * NCLS));
}

extern "C" void kernel_launch(void* const* d_in, const int* in_sizes, int n_in,
                              void* d_out, int out_size, void* d_ws, size_t ws_size,
                              hipStream_t stream) {
  const float* x = (const float*)d_in[0];
  const int* mask = (const int*)d_in[1];
  const float* target = (const float*)d_in[2];
  const float* Wa1 = (const float*)d_in[3];
  const float* ba1 = (const float*)d_in[4];
  const float* Wa2 = (const float*)d_in[5];
  const float* ba2 = (const float*)d_in[6];
  const float* Wh = (const float*)d_in[7];
  const float* bh = (const float*)d_in[8];
  float* out = (float*)d_out;

  char* ws = (char*)d_ws;
  float* sums = (float*)ws;
  float* counts = (float*)(ws + OFF_COUNTS);
  float* alog = (float*)(ws + OFF_ALOG);
  float* wloss = (float*)(ws + OFF_WLOSS);
  unsigned char* ids = (unsigned char*)(ws + OFF_IDS);

  k_zero<<<513, 256, 0, stream>>>((float4*)ws);
  k_ids_counts<<<dim3(4, NB), 256, 0, stream>>>(mask, ids, counts);
  k_segmeans<<<dim3(8, 4, NB), 256, 0, stream>>>(x, ids, sums);
  k_att<<<dim3(16, NB), 256, 0, stream>>>(sums, counts, Wa1, ba1, Wa2, ba2, alog);
  k_head<<<NB, 256, 0, stream>>>(sums, counts, alog, Wh, bh, target, out, wloss);
  k_loss<<<1, 64, 0, stream>>>(wloss, out);
}